// Round 1
// baseline (82.502 us; speedup 1.0000x reference)
//
#include <hip/hip_runtime.h>

#define NCAM   6
#define FHW    72        // FH*FW
#define EMBED  128
#define NG     432       // gaussians per scale
#define NGP    448       // padded (64 lanes * 7)
#define THRESH 0.01f
#define AMIN   (1.0f/255.0f)

struct ScalePtrs {
    const float* feat;
    const float* mean;
    const float* unc;
    const float* opac;
};

// ---------------- per-gaussian parameter prep ----------------
// prm layout per scale: 6 SoA arrays of NGP floats: pr, pc, qa, qb, qc, ok
__global__ void prep_params(ScalePtrs sp0, ScalePtrs sp1, ScalePtrs sp2, ScalePtrs sp3,
                            float* __restrict__ prm)
{
    int idx = blockIdx.x * blockDim.x + threadIdx.x;
    if (idx >= 4 * NGP) return;
    int s = idx / NGP, j = idx - s * NGP;
    ScalePtrs sp = (s == 0) ? sp0 : (s == 1) ? sp1 : (s == 2) ? sp2 : sp3;
    float H = (s == 0) ? 25.f : (s == 1) ? 50.f : (s == 2) ? 100.f : 200.f;
    float* base = prm + s * 6 * NGP;

    float pr = 0.f, pc = 0.f, qa = 0.f, qb = 0.f, qc = 0.f, ok = 0.f;
    if (j < NG) {
        float sh = H * 0.01f;          // sw == sh (square images)
        float m0 = sp.mean[j * 3 + 0];
        float m1 = sp.mean[j * 3 + 1];
        float u00 = fmaxf(sp.unc[j * 9 + 0], 1.f);
        float u01 = fmaxf(sp.unc[j * 9 + 1], 1.f);
        float u11 = fmaxf(sp.unc[j * 9 + 4], 1.f);
        float o = sp.opac[j];
        pr = -sh * m1 + H * 0.5f;
        pc = -sh * m0 + H * 0.5f;
        float va = sh * sh * u11 + 0.3f;
        float vb = sh * sh * u01;
        float vc = sh * sh * u00 + 0.3f;
        float det = va * vc - vb * vb;
        bool keep = (o > THRESH) && (det > 0.f);
        if (keep) {
            float inv = 1.f / det;
            qa = 0.5f * vc * inv;      // coeff of dr^2
            qc = 0.5f * va * inv;      // coeff of dc^2
            qb = vb * inv;             // coeff of dr*dc
            ok = o;
        }
        // !keep: all-zero coeffs -> power = 0 -> alpha = min(0,0.99)=0 -> culled, NaN-free
    }
    base[0 * NGP + j] = pr;
    base[1 * NGP + j] = pc;
    base[2 * NGP + j] = qa;
    base[3 * NGP + j] = qb;
    base[4 * NGP + j] = qc;
    base[5 * NGP + j] = ok;
}

// ---------------- feature transpose: ft[s][n][d] = feat[cam][d][hw] ----------------
__global__ void prep_ft(ScalePtrs sp0, ScalePtrs sp1, ScalePtrs sp2, ScalePtrs sp3,
                        float* __restrict__ ft)
{
    int bn = blockIdx.x;               // 0 .. 4*NG-1
    int s = bn / NG, n = bn - s * NG;
    const float* feat = (s == 0) ? sp0.feat : (s == 1) ? sp1.feat : (s == 2) ? sp2.feat : sp3.feat;
    int cam = n / FHW, hw = n - cam * FHW;
    int d = threadIdx.x;               // 0..127
    ft[bn * EMBED + d] = feat[cam * (EMBED * FHW) + d * FHW + hw];
}

// ---------------- num_gaussians ----------------
__global__ void count_g(const float* __restrict__ o0, const float* __restrict__ o1,
                        const float* __restrict__ o2, const float* __restrict__ o3,
                        float* __restrict__ out_num)
{
    __shared__ float red[256];
    int t = threadIdx.x;
    float cnt = 0.f;
    const float* os[4] = {o0, o1, o2, o3};
    for (int s = 0; s < 4; s++)
        for (int i = t; i < NG; i += 256)
            cnt += (os[s][i] > THRESH) ? 1.f : 0.f;
    red[t] = cnt;
    __syncthreads();
    for (int st = 128; st > 0; st >>= 1) {
        if (t < st) red[t] += red[t + st];
        __syncthreads();
    }
    if (t == 0) *out_num = red[0];
}

// ---------------- render: one wave per pixel ----------------
__global__ __launch_bounds__(256) void render(const float* __restrict__ ft,
                                              const float* __restrict__ prm,
                                              float* __restrict__ out,
                                              int H, int P)
{
    __shared__ float s_pr[NGP], s_pc[NGP], s_qa[NGP], s_qb[NGP], s_qc[NGP], s_ok[NGP];
    __shared__ int   s_cn[4][NGP];
    __shared__ float s_cw[4][NGP];

    int t = threadIdx.x;
    for (int i = t; i < NGP; i += 256) {
        s_pr[i] = prm[0 * NGP + i];
        s_pc[i] = prm[1 * NGP + i];
        s_qa[i] = prm[2 * NGP + i];
        s_qb[i] = prm[3 * NGP + i];
        s_qc[i] = prm[4 * NGP + i];
        s_ok[i] = prm[5 * NGP + i];
    }
    __syncthreads();

    int wave = t >> 6, lane = t & 63;
    int p = blockIdx.x * 4 + wave;
    int row = p / H;
    int col = p - row * H;
    float fr = (float)row, fc = (float)col;

    // phase 1: alphas for this lane's 7 contiguous gaussians
    float alpha[7];
    float om = 1.f;
    int n0 = lane * 7;
    #pragma unroll
    for (int i = 0; i < 7; i++) {
        int n = n0 + i;
        float dr = s_pr[n] - fr;
        float dc = s_pc[n] - fc;
        float power = s_qb[n] * dr * dc - s_qa[n] * dr * dr - s_qc[n] * dc * dc;
        float a = 0.f;
        if (power <= 0.f) {
            a = fminf(s_ok[n] * __expf(power), 0.99f);
            if (a < AMIN) a = 0.f;
        }
        alpha[i] = a;
        om *= (1.f - a);
    }

    // phase 2: cross-lane product scan -> exclusive transmittance per lane chunk
    float incl = om;
    #pragma unroll
    for (int off = 1; off < 64; off <<= 1) {
        float v = __shfl_up(incl, off, 64);
        if (lane >= off) incl *= v;
    }
    float T = __shfl_up(incl, 1, 64);
    if (lane == 0) T = 1.f;

    float w[7];
    int cnt = 0;
    #pragma unroll
    for (int i = 0; i < 7; i++) {
        float wi = alpha[i] * T;
        T *= (1.f - alpha[i]);
        w[i] = wi;
        cnt += (wi > 0.f) ? 1 : 0;
    }

    // compact (n, w) pairs into per-wave LDS list
    int incc = cnt;
    #pragma unroll
    for (int off = 1; off < 64; off <<= 1) {
        int v = __shfl_up(incc, off, 64);
        if (lane >= off) incc += v;
    }
    int base = incc - cnt;
    int tot = __shfl(incc, 63, 64);
    #pragma unroll
    for (int i = 0; i < 7; i++) {
        if (w[i] > 0.f) {
            s_cn[wave][base] = n0 + i;
            s_cw[wave][base] = w[i];
            base++;
        }
    }
    __syncthreads();

    // phase 3: sparse accumulate, lanes = channels (coalesced ft rows)
    float acc0 = 0.f, acc1 = 0.f;
    for (int j = 0; j < tot; j++) {
        int n = s_cn[wave][j];
        float wg = s_cw[wave][j];
        acc0 += wg * ft[n * EMBED + lane];
        acc1 += wg * ft[n * EMBED + 64 + lane];
    }

    if (p < P) {
        out[lane * P + p]        = acc0;
        out[(lane + 64) * P + p] = acc1;
    }
}

extern "C" void kernel_launch(void* const* d_in, const int* in_sizes, int n_in,
                              void* d_out, int out_size, void* d_ws, size_t ws_size,
                              hipStream_t stream)
{
    // setup_inputs() dict order: features{s}, means{s}, uncert{s}, opac{s} for s=0..3, then b, n
    ScalePtrs sp[4];
    for (int s = 0; s < 4; s++) {
        sp[s].feat = (const float*)d_in[4 * s + 0];
        sp[s].mean = (const float*)d_in[4 * s + 1];
        sp[s].unc  = (const float*)d_in[4 * s + 2];
        sp[s].opac = (const float*)d_in[4 * s + 3];
    }

    float* ws  = (float*)d_ws;
    float* ft  = ws;                       // 4*432*128 floats
    float* prm = ws + 4 * NG * EMBED;      // 4*6*448 floats
    float* out = (float*)d_out;

    prep_params<<<(4 * NGP + 255) / 256, 256, 0, stream>>>(sp[0], sp[1], sp[2], sp[3], prm);
    prep_ft<<<4 * NG, EMBED, 0, stream>>>(sp[0], sp[1], sp[2], sp[3], ft);
    count_g<<<1, 256, 0, stream>>>(sp[0].opac, sp[1].opac, sp[2].opac, sp[3].opac,
                                   out + 6800000);

    const int Hs[4]       = {25, 50, 100, 200};
    const long long offs[4] = {0, 80000, 400000, 1680000};
    for (int s = 0; s < 4; s++) {
        int P = Hs[s] * Hs[s];
        render<<<(P + 3) / 4, 256, 0, stream>>>(ft + (long long)s * NG * EMBED,
                                                prm + s * 6 * NGP,
                                                out + offs[s], Hs[s], P);
    }
}

// Round 2
// 81.300 us; speedup vs baseline: 1.0148x; 1.0148x over previous
//
#include <hip/hip_runtime.h>

#define NCAM   6
#define FHW    72        // FH*FW
#define EMBED  128
#define NG     432       // gaussians per scale
#define NGP    448       // padded stride in prm
#define THRESH 0.01f
#define AMIN   (1.0f/255.0f)
#define BCAP   432       // max band-list length

// band counts per scale: ceil(H/4) = {7, 13, 25, 50}, offsets {0,7,20,45}, total 95

struct PrepArgs {
    const float* feat[4];
    const float* mean[4];
    const float* unc[4];
    const float* opac[4];
    float* ft;            // [4][432][128]
    float* prm;           // [4][6][448]: pr, pc, qa, qb, qc, ok
    int* blen;            // [95]
    unsigned short* bls;  // [95][432]
    float* outnum;
};

// roles by blockIdx.x: [0,7) prep_params, [7,871) ft transpose,
// [871,966) band build, 966 count
__global__ __launch_bounds__(256) void fused_prep(PrepArgs a)
{
    int b = blockIdx.x, t = threadIdx.x;
    if (b < 7) {
        int idx = b * 256 + t;
        if (idx >= 4 * NGP) return;
        int s = idx / NGP, j = idx - s * NGP;
        float H = (s == 0) ? 25.f : (s == 1) ? 50.f : (s == 2) ? 100.f : 200.f;
        float* base = a.prm + s * 6 * NGP;
        float pr = 0.f, pc = 0.f, qa = 0.f, qb = 0.f, qc = 0.f, ok = 0.f;
        if (j < NG) {
            float sh = H * 0.01f;
            float m0 = a.mean[s][j * 3 + 0], m1 = a.mean[s][j * 3 + 1];
            float u00 = fmaxf(a.unc[s][j * 9 + 0], 1.f);
            float u01 = fmaxf(a.unc[s][j * 9 + 1], 1.f);
            float u11 = fmaxf(a.unc[s][j * 9 + 4], 1.f);
            float o = a.opac[s][j];
            pr = -sh * m1 + H * 0.5f;
            pc = -sh * m0 + H * 0.5f;
            float va = sh * sh * u11 + 0.3f;
            float vb = sh * sh * u01;
            float vc = sh * sh * u00 + 0.3f;
            float det = va * vc - vb * vb;
            if (o > THRESH && det > 0.f) {
                float inv = 1.f / det;
                qa = 0.5f * vc * inv;   // dr^2 coeff
                qc = 0.5f * va * inv;   // dc^2 coeff
                qb = vb * inv;          // dr*dc coeff
                ok = o;
            }
        }
        base[0 * NGP + j] = pr; base[1 * NGP + j] = pc; base[2 * NGP + j] = qa;
        base[3 * NGP + j] = qb; base[4 * NGP + j] = qc; base[5 * NGP + j] = ok;
    } else if (b < 871) {
        int e = (b - 7) * 256 + t;            // < 221184
        int bn = e >> 7, d = e & 127;
        int s = (bn < 432) ? 0 : (bn < 864) ? 1 : (bn < 1296) ? 2 : 3;
        int n = bn - s * 432;
        int cam = n / FHW, hw = n - cam * FHW;
        a.ft[e] = a.feat[s][cam * (EMBED * FHW) + d * FHW + hw];
    } else if (b < 966) {
        if (t >= 64) return;
        int g = b - 871;
        int lane = t;
        int s = (g < 7) ? 0 : (g < 20) ? 1 : (g < 45) ? 2 : 3;
        int boff = (s == 0) ? 0 : (s == 1) ? 7 : (s == 2) ? 20 : 45;
        int band = g - boff;
        int H = (s == 0) ? 25 : (s == 1) ? 50 : (s == 2) ? 100 : 200;
        float sh = H * 0.01f;
        float r0 = (float)(band * 4);
        float r1 = (float)min(band * 4 + 3, H - 1);
        const float* mean = a.mean[s];
        const float* unc  = a.unc[s];
        const float* opac = a.opac[s];
        int base = 0;
        for (int i = 0; i < 7; i++) {
            int n = i * 64 + lane;
            bool act = false;
            if (n < NG) {
                float m1 = mean[n * 3 + 1];
                float u00 = fmaxf(unc[n * 9 + 0], 1.f);
                float u01 = fmaxf(unc[n * 9 + 1], 1.f);
                float u11 = fmaxf(unc[n * 9 + 4], 1.f);
                float o = opac[n];
                float va = sh * sh * u11 + 0.3f;
                float vb = sh * sh * u01;
                float vc = sh * sh * u00 + 0.3f;
                float det = va * vc - vb * vb;
                if (o > THRESH && det > 0.f) {
                    float pr = -sh * m1 + H * 0.5f;
                    float thr = __logf(255.f * o);           // alpha>=AMIN bound
                    float Rr = sqrtf(2.f * va * thr) + 1e-3f; // max power over dc = -dr^2/(2va)
                    act = (pr >= r0 - Rr) && (pr <= r1 + Rr);
                }
            }
            unsigned long long m = __ballot(act);
            int pos = base + __popcll(m & ((1ull << lane) - 1ull));
            if (act) a.bls[g * BCAP + pos] = (unsigned short)n;
            base += __popcll(m);
        }
        if (lane == 0) a.blen[g] = base;
    } else {
        __shared__ float red[256];
        float cnt = 0.f;
        for (int s = 0; s < 4; s++)
            for (int i = t; i < NG; i += 256)
                cnt += (a.opac[s][i] > THRESH) ? 1.f : 0.f;
        red[t] = cnt;
        __syncthreads();
        for (int st = 128; st > 0; st >>= 1) {
            if (t < st) red[t] += red[t + st];
            __syncthreads();
        }
        if (t == 0) *a.outnum = red[0];
    }
}

// tile = 4 rows x 16 cols; thread = (pixel lane&63, channel-quarter lane>>6)
// blocks: s0 [0,14), s1 [14,66), s2 [66,241), s3 [241,891)
__global__ __launch_bounds__(256) void render_all(const float* __restrict__ ws_ft,
                                                  const float* __restrict__ prm,
                                                  const unsigned short* __restrict__ bls,
                                                  const int* __restrict__ blen,
                                                  float* __restrict__ out)
{
    __shared__ float s_pr[BCAP], s_pc[BCAP], s_qa[BCAP], s_qb[BCAP], s_qc[BCAP], s_ok[BCAP];
    __shared__ int s_n[BCAP];

    int b = blockIdx.x, t = threadIdx.x;
    int s, tb;
    if (b < 14)       { s = 0; tb = b; }
    else if (b < 66)  { s = 1; tb = b - 14; }
    else if (b < 241) { s = 2; tb = b - 66; }
    else              { s = 3; tb = b - 241; }
    int H = (s == 0) ? 25 : (s == 1) ? 50 : (s == 2) ? 100 : 200;
    int chunks = (H + 15) >> 4;
    int band = tb / chunks, chunk = tb - band * chunks;
    int gband = ((s == 0) ? 0 : (s == 1) ? 7 : (s == 2) ? 20 : 45) + band;
    int P = H * H;
    const float* ft = ws_ft + s * (NG * EMBED);
    const float* pb = prm + s * 6 * NGP;
    float* o = out + ((s == 0) ? 0 : (s == 1) ? 80000 : (s == 2) ? 400000 : 1680000);

    int len = blen[gband];
    const unsigned short* bl = bls + gband * BCAP;
    for (int j = t; j < len; j += 256) {
        int n = bl[j];
        s_n[j]  = n;
        s_pr[j] = pb[0 * NGP + n];
        s_pc[j] = pb[1 * NGP + n];
        s_qa[j] = pb[2 * NGP + n];
        s_qb[j] = pb[3 * NGP + n];
        s_qc[j] = pb[4 * NGP + n];
        s_ok[j] = pb[5 * NGP + n];
    }
    __syncthreads();

    int lane = t & 63, q = t >> 6;
    int r = lane >> 4, c = lane & 15;
    int row = band * 4 + r, col = chunk * 16 + c;
    float frow = (float)row, fcol = (float)col;
    const float* ftq = ft + q * 32;

    float acc[32];
    #pragma unroll
    for (int i = 0; i < 32; i++) acc[i] = 0.f;
    float T = 1.f;

    for (int j = 0; j < len; j++) {
        float dr = s_pr[j] - frow;
        float dc = s_pc[j] - fcol;
        float power = s_qb[j] * dr * dc - s_qa[j] * dr * dr - s_qc[j] * dc * dc;
        float aL = 0.f;
        if (power <= 0.f) {
            aL = fminf(s_ok[j] * __expf(power), 0.99f);
            aL = (aL >= AMIN) ? aL : 0.f;
        }
        float w = aL * T;
        T *= (1.f - aL);
        if (__any(w > 0.f)) {
            const float* fr = ftq + s_n[j] * EMBED;
            #pragma unroll
            for (int i = 0; i < 32; i += 4) {
                float4 f4 = *reinterpret_cast<const float4*>(fr + i);
                acc[i]     += w * f4.x;
                acc[i + 1] += w * f4.y;
                acc[i + 2] += w * f4.z;
                acc[i + 3] += w * f4.w;
            }
        }
    }

    if (row < H && col < H) {
        int pp = row * H + col;
        #pragma unroll
        for (int i = 0; i < 32; i++)
            out[0], o[(q * 32 + i) * P + pp] = acc[i];
    }
}

extern "C" void kernel_launch(void* const* d_in, const int* in_sizes, int n_in,
                              void* d_out, int out_size, void* d_ws, size_t ws_size,
                              hipStream_t stream)
{
    PrepArgs a;
    for (int s = 0; s < 4; s++) {
        a.feat[s] = (const float*)d_in[4 * s + 0];
        a.mean[s] = (const float*)d_in[4 * s + 1];
        a.unc[s]  = (const float*)d_in[4 * s + 2];
        a.opac[s] = (const float*)d_in[4 * s + 3];
    }
    float* ws = (float*)d_ws;
    a.ft   = ws;                                    // 221184 floats
    a.prm  = ws + 221184;                           // 10752 floats
    a.blen = (int*)(ws + 231936);                   // 95 ints
    a.bls  = (unsigned short*)(ws + 232032);        // 95*432 u16
    a.outnum = (float*)d_out + 6800000;

    fused_prep<<<967, 256, 0, stream>>>(a);
    render_all<<<891, 256, 0, stream>>>(a.ft, a.prm, a.bls, a.blen, (float*)d_out);
}

// Round 3
// 59.714 us; speedup vs baseline: 1.3816x; 1.3615x over previous
//
#include <hip/hip_runtime.h>

#define NCAM   6
#define FHW    72        // FH*FW
#define EMBED  128
#define NG     432       // gaussians per scale
#define NGP    448       // padded stride in prm
#define THRESH 0.01f
#define AMIN   (1.0f/255.0f)
#define TCAP   432       // tile-list capacity
#define NTILES 891
// tiles are 4 rows x 16 cols:
// s0: 7 bands x 2 chunks  = 14    tiles [0,14)
// s1: 13 x 4              = 52    tiles [14,66)
// s2: 25 x 7              = 175   tiles [66,241)
// s3: 50 x 13             = 650   tiles [241,891)

struct PrepArgs {
    const float* feat[4];
    const float* mean[4];
    const float* unc[4];
    const float* opac[4];
    float* ft;            // [4][432][128]
    float* prm;           // [4][6][448]: pr, pc, qa, qb, qc, ok
    int* tlen;            // [891]
    unsigned short* tls;  // [891][432]
    float* outnum;
};

__device__ __forceinline__ void tile_decode(int g, int& s, int& H, int& band, int& chunk)
{
    int tb;
    if (g < 14)       { s = 0; H = 25;  tb = g;       chunk = tb & 1;  band = tb >> 1; return; }
    else if (g < 66)  { s = 1; H = 50;  tb = g - 14;  chunk = tb & 3;  band = tb >> 2; return; }
    else if (g < 241) { s = 2; H = 100; tb = g - 66;  band = tb / 7;   chunk = tb - band * 7; return; }
    else              { s = 3; H = 200; tb = g - 241; band = tb / 13;  chunk = tb - band * 13; return; }
}

// roles by blockIdx.x: [0,7) params, [7,871) ft transpose, [871,1762) tile lists, 1762 count
__global__ __launch_bounds__(256) void fused_prep(PrepArgs a)
{
    int b = blockIdx.x, t = threadIdx.x;
    if (b < 7) {
        int idx = b * 256 + t;
        if (idx >= 4 * NGP) return;
        int s = idx / NGP, j = idx - s * NGP;
        float H = (s == 0) ? 25.f : (s == 1) ? 50.f : (s == 2) ? 100.f : 200.f;
        float* base = a.prm + s * 6 * NGP;
        float pr = 0.f, pc = 0.f, qa = 0.f, qb = 0.f, qc = 0.f, ok = 0.f;
        if (j < NG) {
            float sh = H * 0.01f;
            float m0 = a.mean[s][j * 3 + 0], m1 = a.mean[s][j * 3 + 1];
            float u00 = fmaxf(a.unc[s][j * 9 + 0], 1.f);
            float u01 = fmaxf(a.unc[s][j * 9 + 1], 1.f);
            float u11 = fmaxf(a.unc[s][j * 9 + 4], 1.f);
            float o = a.opac[s][j];
            pr = -sh * m1 + H * 0.5f;
            pc = -sh * m0 + H * 0.5f;
            float va = sh * sh * u11 + 0.3f;
            float vb = sh * sh * u01;
            float vc = sh * sh * u00 + 0.3f;
            float det = va * vc - vb * vb;
            if (o > THRESH && det > 0.f) {
                float inv = 1.f / det;
                qa = 0.5f * vc * inv;   // dr^2 coeff
                qc = 0.5f * va * inv;   // dc^2 coeff
                qb = vb * inv;          // dr*dc coeff
                ok = o;
            }
        }
        base[0 * NGP + j] = pr; base[1 * NGP + j] = pc; base[2 * NGP + j] = qa;
        base[3 * NGP + j] = qb; base[4 * NGP + j] = qc; base[5 * NGP + j] = ok;
    } else if (b < 871) {
        int e = (b - 7) * 256 + t;            // < 221184
        int bn = e >> 7, d = e & 127;
        int s = (bn < 432) ? 0 : (bn < 864) ? 1 : (bn < 1296) ? 2 : 3;
        int n = bn - s * 432;
        int cam = n / FHW, hw = n - cam * FHW;
        a.ft[e] = a.feat[s][cam * (EMBED * FHW) + d * FHW + hw];
    } else if (b < 871 + NTILES) {
        if (t >= 64) return;
        int g = b - 871;
        int lane = t;
        int s, H, band, chunk;
        tile_decode(g, s, H, band, chunk);
        float sh = H * 0.01f;
        float r0 = (float)(band * 4);
        float r1 = (float)min(band * 4 + 3, H - 1);
        float c0 = (float)(chunk * 16);
        float c1 = (float)min(chunk * 16 + 15, H - 1);
        const float* mean = a.mean[s];
        const float* unc  = a.unc[s];
        const float* opac = a.opac[s];
        int base = 0;
        for (int i = 0; i < 7; i++) {
            int n = i * 64 + lane;
            bool act = false;
            if (n < NG) {
                float m0 = mean[n * 3 + 0], m1 = mean[n * 3 + 1];
                float u00 = fmaxf(unc[n * 9 + 0], 1.f);
                float u01 = fmaxf(unc[n * 9 + 1], 1.f);
                float u11 = fmaxf(unc[n * 9 + 4], 1.f);
                float o = opac[n];
                float va = sh * sh * u11 + 0.3f;
                float vb = sh * sh * u01;
                float vc = sh * sh * u00 + 0.3f;
                float det = va * vc - vb * vb;
                if (o > THRESH && det > 0.f) {
                    float pr = -sh * m1 + H * 0.5f;
                    float pc = -sh * m0 + H * 0.5f;
                    float thr = __logf(255.f * o);           // alpha >= 1/255 level set
                    float Rr = sqrtf(2.f * va * thr) + 1e-2f; // max |dr| on level set
                    float Rc = sqrtf(2.f * vc * thr) + 1e-2f; // max |dc| on level set
                    act = (pr >= r0 - Rr) && (pr <= r1 + Rr) &&
                          (pc >= c0 - Rc) && (pc <= c1 + Rc);
                }
            }
            unsigned long long m = __ballot(act);
            int pos = base + __popcll(m & ((1ull << lane) - 1ull));
            if (act) a.tls[g * TCAP + pos] = (unsigned short)n;
            base += __popcll(m);
        }
        if (lane == 0) a.tlen[g] = base;
    } else {
        __shared__ float red[256];
        float cnt = 0.f;
        for (int s = 0; s < 4; s++)
            for (int i = t; i < NG; i += 256)
                cnt += (a.opac[s][i] > THRESH) ? 1.f : 0.f;
        red[t] = cnt;
        __syncthreads();
        for (int st = 128; st > 0; st >>= 1) {
            if (t < st) red[t] += red[t + st];
            __syncthreads();
        }
        if (t == 0) *a.outnum = red[0];
    }
}

// tile = 4 rows x 16 cols; thread = (pixel = lane, channel-quarter q = t>>6)
__global__ __launch_bounds__(256) void render_all(const float* __restrict__ ws_ft,
                                                  const float* __restrict__ prm,
                                                  const unsigned short* __restrict__ tls,
                                                  const int* __restrict__ tlen,
                                                  float* __restrict__ out)
{
    __shared__ float s_pr[TCAP], s_pc[TCAP], s_qa[TCAP], s_qb[TCAP], s_qc[TCAP], s_ok[TCAP];
    __shared__ int s_n[TCAP];

    int g = blockIdx.x, t = threadIdx.x;
    int s, H, band, chunk;
    tile_decode(g, s, H, band, chunk);
    int P = H * H;
    const float* ft = ws_ft + s * (NG * EMBED);
    const float* pb = prm + s * 6 * NGP;
    float* o = out + ((s == 0) ? 0 : (s == 1) ? 80000 : (s == 2) ? 400000 : 1680000);

    int len = tlen[g];
    const unsigned short* tl = tls + g * TCAP;
    for (int j = t; j < len; j += 256) {
        int n = tl[j];
        s_n[j]  = n * EMBED;
        s_pr[j] = pb[0 * NGP + n];
        s_pc[j] = pb[1 * NGP + n];
        s_qa[j] = pb[2 * NGP + n];
        s_qb[j] = pb[3 * NGP + n];
        s_qc[j] = pb[4 * NGP + n];
        s_ok[j] = pb[5 * NGP + n];
    }
    __syncthreads();

    int lane = t & 63, q = t >> 6;
    int r = lane >> 4, c = lane & 15;
    int row = band * 4 + r, col = chunk * 16 + c;
    float frow = (float)row, fcol = (float)col;
    const float* ftq = ft + q * 32;

    float acc[32];
    #pragma unroll
    for (int i = 0; i < 32; i++) acc[i] = 0.f;
    float T = 1.f;

    if (len > 0) {
        // software pipeline: prefetch params + feature row for j+1 while computing j
        float pr = s_pr[0], pc = s_pc[0], qa = s_qa[0], qb = s_qb[0], qc = s_qc[0], ok = s_ok[0];
        int off = s_n[0];
        float4 f[8];
        #pragma unroll
        for (int i = 0; i < 8; i++)
            f[i] = *reinterpret_cast<const float4*>(ftq + off + i * 4);

        for (int j = 0; j < len; j++) {
            int jn = (j + 1 < len) ? j + 1 : j;
            float prn = s_pr[jn], pcn = s_pc[jn], qan = s_qa[jn];
            float qbn = s_qb[jn], qcn = s_qc[jn], okn = s_ok[jn];
            int offn = s_n[jn];
            float4 fn[8];
            #pragma unroll
            for (int i = 0; i < 8; i++)
                fn[i] = *reinterpret_cast<const float4*>(ftq + offn + i * 4);

            float dr = pr - frow;
            float dc = pc - fcol;
            float power = qb * dr * dc - qa * dr * dr - qc * dc * dc;
            float aL = 0.f;
            if (power <= 0.f) {
                aL = fminf(ok * __expf(power), 0.99f);
                aL = (aL >= AMIN) ? aL : 0.f;
            }
            float w = aL * T;
            T *= (1.f - aL);
            #pragma unroll
            for (int i = 0; i < 8; i++) {
                acc[i * 4]     += w * f[i].x;
                acc[i * 4 + 1] += w * f[i].y;
                acc[i * 4 + 2] += w * f[i].z;
                acc[i * 4 + 3] += w * f[i].w;
            }
            #pragma unroll
            for (int i = 0; i < 8; i++) f[i] = fn[i];
            pr = prn; pc = pcn; qa = qan; qb = qbn; qc = qcn; ok = okn; off = offn;
        }
    }

    if (row < H && col < H) {
        int pp = row * H + col;
        #pragma unroll
        for (int i = 0; i < 32; i++)
            o[(q * 32 + i) * P + pp] = acc[i];
    }
}

extern "C" void kernel_launch(void* const* d_in, const int* in_sizes, int n_in,
                              void* d_out, int out_size, void* d_ws, size_t ws_size,
                              hipStream_t stream)
{
    PrepArgs a;
    for (int s = 0; s < 4; s++) {
        a.feat[s] = (const float*)d_in[4 * s + 0];
        a.mean[s] = (const float*)d_in[4 * s + 1];
        a.unc[s]  = (const float*)d_in[4 * s + 2];
        a.opac[s] = (const float*)d_in[4 * s + 3];
    }
    float* ws = (float*)d_ws;
    a.ft   = ws;                                    // 221184 floats
    a.prm  = ws + 221184;                           // 10752 floats
    a.tlen = (int*)(ws + 231936);                   // 891 ints
    a.tls  = (unsigned short*)(ws + 232827 + 1);    // 891*432 u16 (~770 KB)
    a.outnum = (float*)d_out + 6800000;

    fused_prep<<<871 + NTILES + 1, 256, 0, stream>>>(a);
    render_all<<<NTILES, 256, 0, stream>>>(a.ft, a.prm, a.tls, a.tlen, (float*)d_out);
}

// Round 4
// 39.073 us; speedup vs baseline: 2.1115x; 1.5283x over previous
//
#include <hip/hip_runtime.h>

#define NCAM   6
#define FHW    72        // FH*FW
#define EMBED  128
#define NG     432       // gaussians per scale
#define NGP    448       // padded stride in prm
#define THRESH 0.01f
#define AMIN   (1.0f/255.0f)
#define TCAP   432       // tile-list capacity
#define NTILES 891
#define CHUNK  32
// tiles are 4 rows x 16 cols:
// s0: 7 bands x 2 chunks  = 14    tiles [0,14)
// s1: 13 x 4              = 52    tiles [14,66)
// s2: 25 x 7              = 175   tiles [66,241)
// s3: 50 x 13             = 650   tiles [241,891)

struct PrepArgs {
    const float* feat[4];
    const float* mean[4];
    const float* unc[4];
    const float* opac[4];
    float* ft;            // [4][432][128]
    float* prm;           // [4][6][448]: pr, pc, qa, qb, qc, ok
    int* tlen;            // [891]
    unsigned short* tls;  // [891][432]
    float* outnum;
};

__device__ __forceinline__ void tile_decode(int g, int& s, int& H, int& band, int& chunk)
{
    int tb;
    if (g < 14)       { s = 0; H = 25;  tb = g;       chunk = tb & 1;  band = tb >> 1; return; }
    else if (g < 66)  { s = 1; H = 50;  tb = g - 14;  chunk = tb & 3;  band = tb >> 2; return; }
    else if (g < 241) { s = 2; H = 100; tb = g - 66;  band = tb / 7;   chunk = tb - band * 7; return; }
    else              { s = 3; H = 200; tb = g - 241; band = tb / 13;  chunk = tb - band * 13; return; }
}

// roles by blockIdx.x: [0,7) params, [7,31) ft transpose (4 scales x 6 cams),
// [31,922) tile lists, 922 count
__global__ __launch_bounds__(256) void fused_prep(PrepArgs a)
{
    int b = blockIdx.x, t = threadIdx.x;
    if (b < 7) {
        int idx = b * 256 + t;
        if (idx >= 4 * NGP) return;
        int s = idx / NGP, j = idx - s * NGP;
        float H = (s == 0) ? 25.f : (s == 1) ? 50.f : (s == 2) ? 100.f : 200.f;
        float* base = a.prm + s * 6 * NGP;
        float pr = 0.f, pc = 0.f, qa = 0.f, qb = 0.f, qc = 0.f, ok = 0.f;
        if (j < NG) {
            float sh = H * 0.01f;
            float m0 = a.mean[s][j * 3 + 0], m1 = a.mean[s][j * 3 + 1];
            float u00 = fmaxf(a.unc[s][j * 9 + 0], 1.f);
            float u01 = fmaxf(a.unc[s][j * 9 + 1], 1.f);
            float u11 = fmaxf(a.unc[s][j * 9 + 4], 1.f);
            float o = a.opac[s][j];
            pr = -sh * m1 + H * 0.5f;
            pc = -sh * m0 + H * 0.5f;
            float va = sh * sh * u11 + 0.3f;
            float vb = sh * sh * u01;
            float vc = sh * sh * u00 + 0.3f;
            float det = va * vc - vb * vb;
            if (o > THRESH && det > 0.f) {
                float inv = 1.f / det;
                qa = 0.5f * vc * inv;   // dr^2 coeff
                qc = 0.5f * va * inv;   // dc^2 coeff
                qb = vb * inv;          // dr*dc coeff
                ok = o;
            }
        }
        base[0 * NGP + j] = pr; base[1 * NGP + j] = pc; base[2 * NGP + j] = qa;
        base[3 * NGP + j] = qb; base[4 * NGP + j] = qc; base[5 * NGP + j] = ok;
    } else if (b < 31) {
        // LDS-staged transpose of one camera's features: coalesced read + write
        __shared__ float l[EMBED * 73];
        int sc = b - 7;
        int s = sc / NCAM, cam = sc - s * NCAM;
        const float* src = a.feat[s] + cam * (EMBED * FHW);
        for (int i = t; i < EMBED * FHW; i += 256) {
            int d = i / FHW, hw = i - d * FHW;
            l[d * 73 + hw] = src[i];
        }
        __syncthreads();
        float* dst = a.ft + (s * NG + cam * FHW) * EMBED;
        for (int e = t; e < EMBED * FHW; e += 256) {
            int hw = e >> 7, d = e & 127;
            dst[hw * EMBED + d] = l[d * 73 + hw];
        }
    } else if (b < 31 + NTILES) {
        if (t >= 64) return;
        int g = b - 31;
        int lane = t;
        int s, H, band, chunk;
        tile_decode(g, s, H, band, chunk);
        float sh = H * 0.01f;
        float r0 = (float)(band * 4);
        float r1 = (float)min(band * 4 + 3, H - 1);
        float c0 = (float)(chunk * 16);
        float c1 = (float)min(chunk * 16 + 15, H - 1);
        const float* mean = a.mean[s];
        const float* unc  = a.unc[s];
        const float* opac = a.opac[s];
        int base = 0;
        for (int i = 0; i < 7; i++) {
            int n = i * 64 + lane;
            bool act = false;
            if (n < NG) {
                float m0 = mean[n * 3 + 0], m1 = mean[n * 3 + 1];
                float u00 = fmaxf(unc[n * 9 + 0], 1.f);
                float u01 = fmaxf(unc[n * 9 + 1], 1.f);
                float u11 = fmaxf(unc[n * 9 + 4], 1.f);
                float o = opac[n];
                float va = sh * sh * u11 + 0.3f;
                float vb = sh * sh * u01;
                float vc = sh * sh * u00 + 0.3f;
                float det = va * vc - vb * vb;
                if (o > THRESH && det > 0.f) {
                    float pr = -sh * m1 + H * 0.5f;
                    float pc = -sh * m0 + H * 0.5f;
                    float thr = __logf(255.f * o);            // alpha >= 1/255 level set
                    float Rr = sqrtf(2.f * va * thr) + 1e-2f; // max |dr| on level set
                    float Rc = sqrtf(2.f * vc * thr) + 1e-2f; // max |dc| on level set
                    act = (pr >= r0 - Rr) && (pr <= r1 + Rr) &&
                          (pc >= c0 - Rc) && (pc <= c1 + Rc);
                }
            }
            unsigned long long m = __ballot(act);
            int pos = base + __popcll(m & ((1ull << lane) - 1ull));
            if (act) a.tls[g * TCAP + pos] = (unsigned short)n;
            base += __popcll(m);
        }
        if (lane == 0) a.tlen[g] = base;
    } else {
        __shared__ float red[256];
        float cnt = 0.f;
        for (int s = 0; s < 4; s++)
            for (int i = t; i < NG; i += 256)
                cnt += (a.opac[s][i] > THRESH) ? 1.f : 0.f;
        red[t] = cnt;
        __syncthreads();
        for (int st = 128; st > 0; st >>= 1) {
            if (t < st) red[t] += red[t + st];
            __syncthreads();
        }
        if (t == 0) *a.outnum = red[0];
    }
}

// block = (tile g, channel-quarter qb); 256 threads = (pixel lane, wave q -> 8 channels)
// alpha computed once per block into LDS (chunks of 32), T-scan redundant per wave,
// feature rows prefetched at distance 2 in two named register slots.
__global__ __launch_bounds__(256) void render_all(const float* __restrict__ ws_ft,
                                                  const float* __restrict__ prm,
                                                  const unsigned short* __restrict__ tls,
                                                  const int* __restrict__ tlen,
                                                  float* __restrict__ out)
{
    __shared__ float s_pr[TCAP], s_pc[TCAP], s_qa[TCAP], s_qb[TCAP], s_qc[TCAP], s_ok[TCAP];
    __shared__ int   s_off[TCAP];
    __shared__ float s_a[CHUNK][64];

    int bb = blockIdx.x, t = threadIdx.x;
    int g = bb >> 2, qb = bb & 3;
    int s, H, band, chunk;
    tile_decode(g, s, H, band, chunk);
    int P = H * H;
    const float* ftb = ws_ft + s * (NG * EMBED);
    const float* pb = prm + s * 6 * NGP;
    float* o = out + ((s == 0) ? 0 : (s == 1) ? 80000 : (s == 2) ? 400000 : 1680000);

    int len = tlen[g];
    const unsigned short* tl = tls + g * TCAP;
    for (int j = t; j < len; j += 256) {
        int n = tl[j];
        s_off[j] = n * EMBED;
        s_pr[j] = pb[0 * NGP + n];
        s_pc[j] = pb[1 * NGP + n];
        s_qa[j] = pb[2 * NGP + n];
        s_qb[j] = pb[3 * NGP + n];
        s_qc[j] = pb[4 * NGP + n];
        s_ok[j] = pb[5 * NGP + n];
    }
    __syncthreads();

    int lane = t & 63, q = t >> 6;
    int r = lane >> 4, c = lane & 15;
    int row = band * 4 + r, col = chunk * 16 + c;
    float frow = (float)row, fcol = (float)col;
    int choff = qb * 32 + q * 8;

    float acc[8];
    #pragma unroll
    for (int i = 0; i < 8; i++) acc[i] = 0.f;
    float T = 1.f;

    float4 fA0, fA1, fB0, fB1;
    if (len > 0) {
        const float* p0 = ftb + s_off[0] + choff;
        fA0 = *reinterpret_cast<const float4*>(p0);
        fA1 = *reinterpret_cast<const float4*>(p0 + 4);
        const float* p1 = ftb + s_off[(len > 1) ? 1 : 0] + choff;
        fB0 = *reinterpret_cast<const float4*>(p1);
        fB1 = *reinterpret_cast<const float4*>(p1 + 4);
    }

    for (int c0 = 0; c0 < len; c0 += CHUNK) {
        int kmax = min(CHUNK, len - c0);
        // phase A: alpha for 32 list entries, each j computed by exactly one wave
        #pragma unroll
        for (int i = 0; i < 8; i++) {
            int k = q * 8 + i;
            if (k < kmax) {
                int j = c0 + k;
                float dr = s_pr[j] - frow;
                float dc = s_pc[j] - fcol;
                float power = s_qb[j] * dr * dc - s_qa[j] * dr * dr - s_qc[j] * dc * dc;
                float aL = 0.f;
                if (power <= 0.f) {
                    aL = fminf(s_ok[j] * __expf(power), 0.99f);
                    aL = (aL >= AMIN) ? aL : 0.f;
                }
                s_a[k][lane] = aL;
            }
        }
        __syncthreads();
        // phase B: scan + accumulate, dist-2 pipelined feature loads
        for (int k = 0; k < kmax; k += 2) {
            {
                float aL = s_a[k][lane];
                float w = aL * T;
                T *= (1.f - aL);
                acc[0] += w * fA0.x; acc[1] += w * fA0.y;
                acc[2] += w * fA0.z; acc[3] += w * fA0.w;
                acc[4] += w * fA1.x; acc[5] += w * fA1.y;
                acc[6] += w * fA1.z; acc[7] += w * fA1.w;
                int jn = c0 + k + 2; jn = (jn < len) ? jn : len - 1;
                const float* pn = ftb + s_off[jn] + choff;
                fA0 = *reinterpret_cast<const float4*>(pn);
                fA1 = *reinterpret_cast<const float4*>(pn + 4);
            }
            if (k + 1 < kmax) {
                float aL = s_a[k + 1][lane];
                float w = aL * T;
                T *= (1.f - aL);
                acc[0] += w * fB0.x; acc[1] += w * fB0.y;
                acc[2] += w * fB0.z; acc[3] += w * fB0.w;
                acc[4] += w * fB1.x; acc[5] += w * fB1.y;
                acc[6] += w * fB1.z; acc[7] += w * fB1.w;
                int jn = c0 + k + 3; jn = (jn < len) ? jn : len - 1;
                const float* pn = ftb + s_off[jn] + choff;
                fB0 = *reinterpret_cast<const float4*>(pn);
                fB1 = *reinterpret_cast<const float4*>(pn + 4);
            }
        }
        __syncthreads();
    }

    if (row < H && col < H) {
        int pp = row * H + col;
        #pragma unroll
        for (int i = 0; i < 8; i++)
            o[(choff + i) * P + pp] = acc[i];
    }
}

extern "C" void kernel_launch(void* const* d_in, const int* in_sizes, int n_in,
                              void* d_out, int out_size, void* d_ws, size_t ws_size,
                              hipStream_t stream)
{
    PrepArgs a;
    for (int s = 0; s < 4; s++) {
        a.feat[s] = (const float*)d_in[4 * s + 0];
        a.mean[s] = (const float*)d_in[4 * s + 1];
        a.unc[s]  = (const float*)d_in[4 * s + 2];
        a.opac[s] = (const float*)d_in[4 * s + 3];
    }
    float* ws = (float*)d_ws;
    a.ft   = ws;                                    // 221184 floats
    a.prm  = ws + 221184;                           // 10752 floats
    a.tlen = (int*)(ws + 231936);                   // 891 ints
    a.tls  = (unsigned short*)(ws + 232828);        // 891*432 u16 (~385 KB)
    a.outnum = (float*)d_out + 6800000;

    fused_prep<<<31 + NTILES + 1, 256, 0, stream>>>(a);
    render_all<<<NTILES * 4, 256, 0, stream>>>(a.ft, a.prm, a.tls, a.tlen, (float*)d_out);
}

// Round 5
// 30.441 us; speedup vs baseline: 2.7102x; 1.2835x over previous
//
#include <hip/hip_runtime.h>

#define NCAM   6
#define FHW    72        // FH*FW
#define EMBED  128
#define NG     432       // gaussians per scale
#define NGP    448       // padded stride in prm
#define THRESH 0.01f
#define AMIN   (1.0f/255.0f)
#define TCAP   432       // tile-list capacity
#define NTILES 891
#define CHUNK  32
// tiles are 4 rows x 16 cols:
// s0: 7 bands x 2 chunks  = 14    tiles [0,14)
// s1: 13 x 4              = 52    tiles [14,66)
// s2: 25 x 7              = 175   tiles [66,241)
// s3: 50 x 13             = 650   tiles [241,891)

struct PrepArgs {
    const float* feat[4];
    const float* mean[4];
    const float* unc[4];
    const float* opac[4];
    float* ft;            // [4][432][128]
    float* prm;           // [4][6][448]: pr, pc, qa, qb, qc, ok
    int* tlen;            // [891]
    unsigned short* tls;  // [891][432]
    float* outnum;
};

__device__ __forceinline__ void tile_decode(int g, int& s, int& H, int& band, int& chunk)
{
    int tb;
    if (g < 14)       { s = 0; H = 25;  tb = g;       chunk = tb & 1;  band = tb >> 1; return; }
    else if (g < 66)  { s = 1; H = 50;  tb = g - 14;  chunk = tb & 3;  band = tb >> 2; return; }
    else if (g < 241) { s = 2; H = 100; tb = g - 66;  band = tb / 7;   chunk = tb - band * 7; return; }
    else              { s = 3; H = 200; tb = g - 241; band = tb / 13;  chunk = tb - band * 13; return; }
}

// roles by blockIdx.x: [0,7) params, [7,31) ft transpose (4 scales x 6 cams),
// [31,922) tile lists, 922 count
__global__ __launch_bounds__(256) void fused_prep(PrepArgs a)
{
    int b = blockIdx.x, t = threadIdx.x;
    if (b < 7) {
        int idx = b * 256 + t;
        if (idx >= 4 * NGP) return;
        int s = idx / NGP, j = idx - s * NGP;
        float H = (s == 0) ? 25.f : (s == 1) ? 50.f : (s == 2) ? 100.f : 200.f;
        float* base = a.prm + s * 6 * NGP;
        float pr = 0.f, pc = 0.f, qa = 0.f, qb = 0.f, qc = 0.f, ok = 0.f;
        if (j < NG) {
            float sh = H * 0.01f;
            float m0 = a.mean[s][j * 3 + 0], m1 = a.mean[s][j * 3 + 1];
            float u00 = fmaxf(a.unc[s][j * 9 + 0], 1.f);
            float u01 = fmaxf(a.unc[s][j * 9 + 1], 1.f);
            float u11 = fmaxf(a.unc[s][j * 9 + 4], 1.f);
            float o = a.opac[s][j];
            pr = -sh * m1 + H * 0.5f;
            pc = -sh * m0 + H * 0.5f;
            float va = sh * sh * u11 + 0.3f;
            float vb = sh * sh * u01;
            float vc = sh * sh * u00 + 0.3f;
            float det = va * vc - vb * vb;
            if (o > THRESH && det > 0.f) {
                float inv = 1.f / det;
                qa = 0.5f * vc * inv;   // dr^2 coeff
                qc = 0.5f * va * inv;   // dc^2 coeff
                qb = vb * inv;          // dr*dc coeff
                ok = o;
            }
        }
        base[0 * NGP + j] = pr; base[1 * NGP + j] = pc; base[2 * NGP + j] = qa;
        base[3 * NGP + j] = qb; base[4 * NGP + j] = qc; base[5 * NGP + j] = ok;
    } else if (b < 31) {
        // LDS-staged transpose of one camera's features: coalesced read + write
        __shared__ float l[EMBED * 73];
        int sc = b - 7;
        int s = sc / NCAM, cam = sc - s * NCAM;
        const float* src = a.feat[s] + cam * (EMBED * FHW);
        for (int i = t; i < EMBED * FHW; i += 256) {
            int d = i / FHW, hw = i - d * FHW;
            l[d * 73 + hw] = src[i];
        }
        __syncthreads();
        float* dst = a.ft + (s * NG + cam * FHW) * EMBED;
        for (int e = t; e < EMBED * FHW; e += 256) {
            int hw = e >> 7, d = e & 127;
            dst[hw * EMBED + d] = l[d * 73 + hw];
        }
    } else if (b < 31 + NTILES) {
        if (t >= 64) return;
        int g = b - 31;
        int lane = t;
        int s, H, band, chunk;
        tile_decode(g, s, H, band, chunk);
        float sh = H * 0.01f;
        float r0 = (float)(band * 4);
        float r1 = (float)min(band * 4 + 3, H - 1);
        float c0 = (float)(chunk * 16);
        float c1 = (float)min(chunk * 16 + 15, H - 1);
        const float* mean = a.mean[s];
        const float* unc  = a.unc[s];
        const float* opac = a.opac[s];
        int base = 0;
        for (int i = 0; i < 7; i++) {
            int n = i * 64 + lane;
            bool act = false;
            if (n < NG) {
                float m0 = mean[n * 3 + 0], m1 = mean[n * 3 + 1];
                float u00 = fmaxf(unc[n * 9 + 0], 1.f);
                float u01 = fmaxf(unc[n * 9 + 1], 1.f);
                float u11 = fmaxf(unc[n * 9 + 4], 1.f);
                float o = opac[n];
                float va = sh * sh * u11 + 0.3f;
                float vb = sh * sh * u01;
                float vc = sh * sh * u00 + 0.3f;
                float det = va * vc - vb * vb;
                if (o > THRESH && det > 0.f) {
                    float pr = -sh * m1 + H * 0.5f;
                    float pc = -sh * m0 + H * 0.5f;
                    float thr = __logf(255.f * o);            // alpha >= 1/255 level set
                    float Rr = sqrtf(2.f * va * thr) + 1e-2f; // max |dr| on level set
                    float Rc = sqrtf(2.f * vc * thr) + 1e-2f; // max |dc| on level set
                    act = (pr >= r0 - Rr) && (pr <= r1 + Rr) &&
                          (pc >= c0 - Rc) && (pc <= c1 + Rc);
                }
            }
            unsigned long long m = __ballot(act);
            int pos = base + __popcll(m & ((1ull << lane) - 1ull));
            if (act) a.tls[g * TCAP + pos] = (unsigned short)n;
            base += __popcll(m);
        }
        if (lane == 0) a.tlen[g] = base;
    } else {
        __shared__ float red[256];
        float cnt = 0.f;
        for (int s = 0; s < 4; s++)
            for (int i = t; i < NG; i += 256)
                cnt += (a.opac[s][i] > THRESH) ? 1.f : 0.f;
        red[t] = cnt;
        __syncthreads();
        for (int st = 128; st > 0; st >>= 1) {
            if (t < st) red[t] += red[t + st];
            __syncthreads();
        }
        if (t == 0) *a.outnum = red[0];
    }
}

// block = (tile g, channel-quarter qb); 256 threads = (pixel lane, wave q -> 8 channels)
// Double-buffered chunk pipeline, ONE sync per chunk:
//   stage(c+1 -> buf^1): coalesced float4 feature loads -> LDS, alphas -> LDS
//   phase B (chunk c, buf): scan + FMAs entirely from LDS (broadcast reads)
__global__ __launch_bounds__(256) void render_all(const float* __restrict__ ws_ft,
                                                  const float* __restrict__ prm,
                                                  const unsigned short* __restrict__ tls,
                                                  const int* __restrict__ tlen,
                                                  float* __restrict__ out)
{
    __shared__ float s_pr[TCAP], s_pc[TCAP], s_qa[TCAP], s_qb[TCAP], s_qc[TCAP], s_ok[TCAP];
    __shared__ int   s_off[TCAP];
    __shared__ float s_a[2][CHUNK][64];
    __shared__ float s_f[2][CHUNK][32];

    int bb = blockIdx.x, t = threadIdx.x;
    int g = bb >> 2, qb = bb & 3;
    int s, H, band, chunk;
    tile_decode(g, s, H, band, chunk);
    int P = H * H;
    const float* ftb = ws_ft + s * (NG * EMBED);
    const float* pb = prm + s * 6 * NGP;
    float* o = out + ((s == 0) ? 0 : (s == 1) ? 80000 : (s == 2) ? 400000 : 1680000);

    int len = tlen[g];
    const unsigned short* tl = tls + g * TCAP;
    for (int j = t; j < len; j += 256) {
        int n = tl[j];
        s_off[j] = n * EMBED;
        s_pr[j] = pb[0 * NGP + n];
        s_pc[j] = pb[1 * NGP + n];
        s_qa[j] = pb[2 * NGP + n];
        s_qb[j] = pb[3 * NGP + n];
        s_qc[j] = pb[4 * NGP + n];
        s_ok[j] = pb[5 * NGP + n];
    }
    __syncthreads();

    int lane = t & 63, q = t >> 6;
    int r = lane >> 4, c = lane & 15;
    int row = band * 4 + r, col = chunk * 16 + c;
    float frow = (float)row, fcol = (float)col;
    int choff = qb * 32 + q * 8;
    int fk = t >> 3, fsub = (t & 7) << 2;   // feature staging mapping

    float acc[8];
    #pragma unroll
    for (int i = 0; i < 8; i++) acc[i] = 0.f;
    float T = 1.f;

    #define STAGE(C0, BUF)                                                          \
    do {                                                                            \
        int kmax_ = min(CHUNK, len - (C0));                                         \
        if (fk < kmax_) {                                                           \
            const float* p_ = ftb + s_off[(C0) + fk] + qb * 32 + fsub;              \
            *reinterpret_cast<float4*>(&s_f[BUF][fk][fsub]) =                       \
                *reinterpret_cast<const float4*>(p_);                               \
        }                                                                           \
        _Pragma("unroll")                                                           \
        for (int i_ = 0; i_ < 8; i_++) {                                            \
            int k_ = q * 8 + i_;                                                    \
            if (k_ < kmax_) {                                                       \
                int j_ = (C0) + k_;                                                 \
                float dr_ = s_pr[j_] - frow;                                        \
                float dc_ = s_pc[j_] - fcol;                                        \
                float pw_ = s_qb[j_] * dr_ * dc_ - s_qa[j_] * dr_ * dr_             \
                            - s_qc[j_] * dc_ * dc_;                                 \
                float aL_ = 0.f;                                                    \
                if (pw_ <= 0.f) {                                                   \
                    aL_ = fminf(s_ok[j_] * __expf(pw_), 0.99f);                     \
                    aL_ = (aL_ >= AMIN) ? aL_ : 0.f;                                \
                }                                                                   \
                s_a[BUF][k_][lane] = aL_;                                           \
            }                                                                       \
        }                                                                           \
    } while (0)

    if (len > 0) {
        STAGE(0, 0);
        __syncthreads();
        int buf = 0;
        for (int c0 = 0; c0 < len; c0 += CHUNK) {
            if (c0 + CHUNK < len) STAGE(c0 + CHUNK, buf ^ 1);
            int kmax = min(CHUNK, len - c0);
            #pragma unroll 4
            for (int k = 0; k < kmax; k++) {
                float aL = s_a[buf][k][lane];
                float w = aL * T;
                T *= (1.f - aL);
                float4 f0 = *reinterpret_cast<const float4*>(&s_f[buf][k][q * 8]);
                float4 f1 = *reinterpret_cast<const float4*>(&s_f[buf][k][q * 8 + 4]);
                acc[0] += w * f0.x; acc[1] += w * f0.y;
                acc[2] += w * f0.z; acc[3] += w * f0.w;
                acc[4] += w * f1.x; acc[5] += w * f1.y;
                acc[6] += w * f1.z; acc[7] += w * f1.w;
            }
            __syncthreads();
            buf ^= 1;
        }
    }
    #undef STAGE

    if (row < H && col < H) {
        int pp = row * H + col;
        #pragma unroll
        for (int i = 0; i < 8; i++)
            o[(choff + i) * P + pp] = acc[i];
    }
}

extern "C" void kernel_launch(void* const* d_in, const int* in_sizes, int n_in,
                              void* d_out, int out_size, void* d_ws, size_t ws_size,
                              hipStream_t stream)
{
    PrepArgs a;
    for (int s = 0; s < 4; s++) {
        a.feat[s] = (const float*)d_in[4 * s + 0];
        a.mean[s] = (const float*)d_in[4 * s + 1];
        a.unc[s]  = (const float*)d_in[4 * s + 2];
        a.opac[s] = (const float*)d_in[4 * s + 3];
    }
    float* ws = (float*)d_ws;
    a.ft   = ws;                                    // 221184 floats
    a.prm  = ws + 221184;                           // 10752 floats
    a.tlen = (int*)(ws + 231936);                   // 891 ints
    a.tls  = (unsigned short*)(ws + 232828);        // 891*432 u16 (~385 KB)
    a.outnum = (float*)d_out + 6800000;

    fused_prep<<<31 + NTILES + 1, 256, 0, stream>>>(a);
    render_all<<<NTILES * 4, 256, 0, stream>>>(a.ft, a.prm, a.tls, a.tlen, (float*)d_out);
}

// Round 6
// 29.188 us; speedup vs baseline: 2.8266x; 1.0429x over previous
//
#include <hip/hip_runtime.h>

#define NCAM   6
#define FHW    72        // FH*FW
#define EMBED  128
#define NG     432       // gaussians per scale
#define THRESH 0.01f
#define AMIN   (1.0f/255.0f)
#define NTILES 891
#define CHUNK  32
// tiles are 4 rows x 16 cols:
// s0: 7 bands x 2 chunks = 14   [0,14)
// s1: 13 x 4             = 52   [14,66)
// s2: 25 x 7             = 175  [66,241)
// s3: 50 x 13            = 650  [241,891)

struct Args {
    const float* feat[4];
    const float* mean[4];
    const float* unc[4];
    const float* opac[4];
    float* out;
};

__device__ __forceinline__ void tile_decode(int g, int& s, int& H, int& band, int& chunk)
{
    int tb;
    if (g < 14)       { s = 0; H = 25;  tb = g;       chunk = tb & 1;  band = tb >> 1; }
    else if (g < 66)  { s = 1; H = 50;  tb = g - 14;  chunk = tb & 3;  band = tb >> 2; }
    else if (g < 241) { s = 2; H = 100; tb = g - 66;  band = tb / 7;   chunk = tb - band * 7; }
    else              { s = 3; H = 200; tb = g - 241; band = tb / 13;  chunk = tb - band * 13; }
}

// ONE kernel. block = (tile g, channel-quarter cq); 256 threads = (pixel lane, wave wv -> 8 ch).
// Prologue: per-block param compute (all 432) + ordered ballot-compact cull into LDS.
// Main loop: double-buffered chunks, T14 split (SLOAD before phase B, SWRITE after).
// Block NTILES*4 computes num_gaussians.
__global__ __launch_bounds__(256) void gauss_render(Args a)
{
    __shared__ float s_pr[NG], s_pc[NG], s_qa[NG], s_qb[NG], s_qc[NG], s_ok[NG];
    __shared__ unsigned short s_list[NG];
    __shared__ int s_cnt[8];
    __shared__ int s_len;
    __shared__ float s_a[2][CHUNK][64];
    __shared__ float s_f[2][CHUNK][32];

    int bb = blockIdx.x, t = threadIdx.x;

    if (bb == NTILES * 4) {          // gaussian count
        __shared__ float red[256];
        float cnt = 0.f;
        for (int s = 0; s < 4; s++)
            for (int i = t; i < NG; i += 256)
                cnt += (a.opac[s][i] > THRESH) ? 1.f : 0.f;
        red[t] = cnt;
        __syncthreads();
        for (int st = 128; st > 0; st >>= 1) {
            if (t < st) red[t] += red[t + st];
            __syncthreads();
        }
        if (t == 0) a.out[6800000] = red[0];
        return;
    }

    int g = bb >> 2, cq = bb & 3;
    int s, H, band, chunk;
    tile_decode(g, s, H, band, chunk);
    int P = H * H;
    float* o = a.out + ((s == 0) ? 0 : (s == 1) ? 80000 : (s == 2) ? 400000 : 1680000);

    int lane = t & 63, wv = t >> 6;
    float sh = H * 0.01f;
    float r0f = (float)(band * 4), r1f = (float)min(band * 4 + 3, H - 1);
    float c0f = (float)(chunk * 16), c1f = (float)min(chunk * 16 + 15, H - 1);
    const float* mean = a.mean[s];
    const float* unc  = a.unc[s];
    const float* opac = a.opac[s];

    // ---- prologue: params + cull (ordered compaction) ----
    bool actv[2]; int rnk[2];
    #pragma unroll
    for (int p = 0; p < 2; p++) {
        int j = p * 256 + t;
        bool act = false;
        if (j < NG) {
            float m0 = mean[j*3+0], m1 = mean[j*3+1];
            float u00 = fmaxf(unc[j*9+0], 1.f);
            float u01 = fmaxf(unc[j*9+1], 1.f);
            float u11 = fmaxf(unc[j*9+4], 1.f);
            float op = opac[j];
            float pr = -sh*m1 + H*0.5f;
            float pc = -sh*m0 + H*0.5f;
            float va = sh*sh*u11 + 0.3f;
            float vb = sh*sh*u01;
            float vc = sh*sh*u00 + 0.3f;
            float det = va*vc - vb*vb;
            float qa = 0.f, qbv = 0.f, qc = 0.f, ok = 0.f;
            if (op > THRESH && det > 0.f) {
                float inv = 1.f/det;
                qa = 0.5f*vc*inv;    // dr^2 coeff
                qc = 0.5f*va*inv;    // dc^2 coeff
                qbv = vb*inv;        // dr*dc coeff
                ok = op;
                float thr = __logf(255.f*op);             // alpha >= 1/255 level set
                float Rr = sqrtf(2.f*va*thr) + 1e-2f;     // max |dr| (det cancels)
                float Rc = sqrtf(2.f*vc*thr) + 1e-2f;     // max |dc|
                act = (pr >= r0f-Rr) && (pr <= r1f+Rr) &&
                      (pc >= c0f-Rc) && (pc <= c1f+Rc);
            }
            s_pr[j]=pr; s_pc[j]=pc; s_qa[j]=qa; s_qb[j]=qbv; s_qc[j]=qc; s_ok[j]=ok;
        }
        unsigned long long m = __ballot(act);
        actv[p] = act;
        rnk[p]  = __popcll(m & ((1ull << lane) - 1ull));
        if (lane == 0) s_cnt[p*4 + wv] = __popcll(m);
    }
    __syncthreads();
    {
        int c[8];
        #pragma unroll
        for (int i = 0; i < 8; i++) c[i] = s_cnt[i];
        int pre0 = 0, pre1 = 0;
        #pragma unroll
        for (int i = 0; i < 8; i++) {
            pre0 += (i < wv) ? c[i] : 0;        // pass 0, wave wv  -> index wv
            pre1 += (i < 4 + wv) ? c[i] : 0;    // pass 1, wave wv  -> index 4+wv
        }
        if (actv[0]) s_list[pre0 + rnk[0]] = (unsigned short)t;
        if (actv[1]) s_list[pre1 + rnk[1]] = (unsigned short)(256 + t);
        if (t == 0) { int tot = 0; for (int i = 0; i < 8; i++) tot += c[i]; s_len = tot; }
    }
    __syncthreads();
    int len = s_len;

    // ---- main loop ----
    int r = lane >> 4, cc = lane & 15;
    int row = band*4 + r, col = chunk*16 + cc;
    float frow = (float)row, fcol = (float)col;
    const float* fbase = a.feat[s];
    int fk = t >> 3, fch = (t & 7) << 2;    // staging: list-row fk, channels cq*32+fch..+3

    float acc[8];
    #pragma unroll
    for (int i = 0; i < 8; i++) acc[i] = 0.f;
    float T = 1.f;
    float4 fst = {0.f, 0.f, 0.f, 0.f};

    #define SLOAD(C0) do {                                                        \
        if (fk < min(CHUNK, len - (C0))) {                                        \
            int n_ = s_list[(C0) + fk];                                           \
            int cam_ = n_ / FHW, hw_ = n_ - cam_ * FHW;                           \
            const float* p_ = fbase + cam_ * (EMBED*FHW)                          \
                              + (cq*32 + fch) * FHW + hw_;                        \
            fst.x = p_[0]; fst.y = p_[FHW]; fst.z = p_[2*FHW]; fst.w = p_[3*FHW]; \
        } } while (0)

    #define SWRITE(C0, BUF) do {                                                  \
        int km_ = min(CHUNK, len - (C0));                                         \
        if (fk < km_)                                                             \
            *reinterpret_cast<float4*>(&s_f[BUF][fk][fch]) = fst;                 \
        _Pragma("unroll")                                                         \
        for (int i_ = 0; i_ < 8; i_++) {                                          \
            int k_ = wv*8 + i_;                                                   \
            if (k_ < km_) {                                                       \
                int n_ = s_list[(C0) + k_];                                       \
                float dr_ = s_pr[n_] - frow;                                      \
                float dc_ = s_pc[n_] - fcol;                                      \
                float pw_ = s_qb[n_]*dr_*dc_ - s_qa[n_]*dr_*dr_                   \
                            - s_qc[n_]*dc_*dc_;                                   \
                float aL_ = 0.f;                                                  \
                if (pw_ <= 0.f) {                                                 \
                    aL_ = fminf(s_ok[n_]*__expf(pw_), 0.99f);                     \
                    aL_ = (aL_ >= AMIN) ? aL_ : 0.f;                              \
                }                                                                 \
                s_a[BUF][k_][lane] = aL_;                                         \
            }                                                                     \
        } } while (0)

    if (len > 0) {
        SLOAD(0);
        SWRITE(0, 0);
        __syncthreads();
        int buf = 0;
        for (int c0 = 0; c0 < len; c0 += CHUNK) {
            bool more = (c0 + CHUNK) < len;
            if (more) SLOAD(c0 + CHUNK);          // global -> regs, hidden under phase B
            int kmax = min(CHUNK, len - c0);
            #pragma unroll 4
            for (int k = 0; k < kmax; k++) {      // phase B: all-LDS composite
                float aL = s_a[buf][k][lane];
                float w = aL * T;
                T *= (1.f - aL);
                float4 f0 = *reinterpret_cast<const float4*>(&s_f[buf][k][wv*8]);
                float4 f1 = *reinterpret_cast<const float4*>(&s_f[buf][k][wv*8 + 4]);
                acc[0] += w*f0.x; acc[1] += w*f0.y; acc[2] += w*f0.z; acc[3] += w*f0.w;
                acc[4] += w*f1.x; acc[5] += w*f1.y; acc[6] += w*f1.z; acc[7] += w*f1.w;
            }
            if (more) SWRITE(c0 + CHUNK, buf ^ 1); // vmcnt drain lands here, post-phase-B
            __syncthreads();
            buf ^= 1;
        }
    }
    #undef SLOAD
    #undef SWRITE

    if (row < H && col < H) {
        int pp = row*H + col;
        int choff = cq*32 + wv*8;
        #pragma unroll
        for (int i = 0; i < 8; i++)
            o[(choff + i)*P + pp] = acc[i];
    }
}

extern "C" void kernel_launch(void* const* d_in, const int* in_sizes, int n_in,
                              void* d_out, int out_size, void* d_ws, size_t ws_size,
                              hipStream_t stream)
{
    Args a;
    for (int s = 0; s < 4; s++) {
        a.feat[s] = (const float*)d_in[4 * s + 0];
        a.mean[s] = (const float*)d_in[4 * s + 1];
        a.unc[s]  = (const float*)d_in[4 * s + 2];
        a.opac[s] = (const float*)d_in[4 * s + 3];
    }
    a.out = (float*)d_out;

    gauss_render<<<NTILES * 4 + 1, 256, 0, stream>>>(a);
}